// Round 3
// baseline (69.403 us; speedup 1.0000x reference)
//
#include <hip/hip_runtime.h>
#include <hip/hip_bf16.h>

typedef __attribute__((ext_vector_type(8))) short short8;
typedef __attribute__((ext_vector_type(4))) float f32x4;

#define OUT_DIM 11008
#define IN_DIM  4096
#define B_DIM   32
#define NT      16                  // output cols per block
#define WAVES   4
#define KW      (IN_DIM / WAVES)    // 1024 k per wave

__device__ __forceinline__ short8 cvt8(const float* __restrict__ src) {
  f32x4 f0 = *reinterpret_cast<const f32x4*>(src);
  f32x4 f1 = *reinterpret_cast<const f32x4*>(src + 4);
  short8 v;
  __hip_bfloat16 h;
  h = __float2bfloat16(f0[0]); v[0] = *reinterpret_cast<short*>(&h);
  h = __float2bfloat16(f0[1]); v[1] = *reinterpret_cast<short*>(&h);
  h = __float2bfloat16(f0[2]); v[2] = *reinterpret_cast<short*>(&h);
  h = __float2bfloat16(f0[3]); v[3] = *reinterpret_cast<short*>(&h);
  h = __float2bfloat16(f1[0]); v[4] = *reinterpret_cast<short*>(&h);
  h = __float2bfloat16(f1[1]); v[5] = *reinterpret_cast<short*>(&h);
  h = __float2bfloat16(f1[2]); v[6] = *reinterpret_cast<short*>(&h);
  h = __float2bfloat16(f1[3]); v[7] = *reinterpret_cast<short*>(&h);
  return v;
}

// Single pass: block = 16 output cols x 32 batch rows; K split across the
// block's 4 waves (1024 k each), combined in LDS. W rows are loaded directly
// from global as MFMA B-fragments (16 rows x 128B contiguous per k-step),
// converted fp32->bf16 in-register. No global partials, no second kernel.
__global__ __launch_bounds__(256, 4)
void bitnet_fused(const float* __restrict__ x,
                  const float* __restrict__ w,
                  const float* __restrict__ scale,
                  float* __restrict__ y)
{
  __shared__ float red[WAVES][64][2][4];   // 8 KB

  const int tid   = threadIdx.x;
  const int lane  = tid & 63;
  const int wv    = tid >> 6;        // wave 0..3 -> k quarter
  const int l15   = lane & 15;
  const int lg    = lane >> 4;       // 0..3 -> k sub-group within MFMA
  const int obase = blockIdx.x * NT;
  const int k0    = wv * KW;

  f32x4 acc0 = (f32x4){0.f, 0.f, 0.f, 0.f};
  f32x4 acc1 = (f32x4){0.f, 0.f, 0.f, 0.f};

  const float* wbase = w + (size_t)(obase + l15) * IN_DIM + k0 + lg * 8;
  const float* xbase = x + (size_t)l15 * IN_DIM + k0 + lg * 8;

#pragma unroll 2
  for (int t = 0; t < KW / 32; ++t) {   // 32 k-steps of 32
    const int kk = t * 32;
    short8 aa0 = cvt8(xbase + kk);
    short8 aa1 = cvt8(xbase + (size_t)16 * IN_DIM + kk);
    short8 bb  = cvt8(wbase + kk);
    acc0 = __builtin_amdgcn_mfma_f32_16x16x32_bf16(aa0, bb, acc0, 0, 0, 0);
    acc1 = __builtin_amdgcn_mfma_f32_16x16x32_bf16(aa1, bb, acc1, 0, 0, 0);
  }

  // cross-wave K-combine in LDS
  *reinterpret_cast<f32x4*>(&red[wv][lane][0][0]) = acc0;
  *reinterpret_cast<f32x4*>(&red[wv][lane][1][0]) = acc1;
  __syncthreads();

  // 512 outputs (32 b x 16 o), 256 threads -> 2 each
  const float sc = scale[0];
#pragma unroll
  for (int e = tid; e < B_DIM * NT; e += 256) {
    const int b  = e >> 4;            // batch row 0..31
    const int oc = e & 15;            // local col
    const int m  = b >> 4;            // frag index
    const int r  = b & 3;             // C/D reg: row = lg*4 + r
    const int lgg = (b >> 2) & 3;
    const int ln  = lgg * 16 + oc;    // source lane
    const float ssum = red[0][ln][m][r] + red[1][ln][m][r]
                     + red[2][ln][m][r] + red[3][ln][m][r];
    y[(size_t)b * OUT_DIM + obase + oc] = ssum * sc;
  }
}

extern "C" void kernel_launch(void* const* d_in, const int* in_sizes, int n_in,
                              void* d_out, int out_size, void* d_ws, size_t ws_size,
                              hipStream_t stream) {
  const float* x = (const float*)d_in[0];
  const float* w = (const float*)d_in[1];
  const float* s = (const float*)d_in[2];
  float* y = (float*)d_out;
  bitnet_fused<<<dim3(OUT_DIM / NT), 256, 0, stream>>>(x, w, s, y);
}

// Round 4
// 47.446 us; speedup vs baseline: 1.4628x; 1.4628x over previous
//
#include <hip/hip_runtime.h>
#include <hip/hip_bf16.h>

typedef __attribute__((ext_vector_type(8))) short short8;
typedef __attribute__((ext_vector_type(4))) float f32x4;

#define OUT_DIM 11008
#define IN_DIM  4096
#define B_DIM   32
#define NT      64      // output cols per block (per wave: all 64)
#define KSPL    8       // K split across blocks
#define KPB     (IN_DIM / KSPL)       // 512 k per block
#define KPW     (KPB / 4)             // 128 k per wave

__device__ __forceinline__ short8 cvt8(const float* __restrict__ src) {
  f32x4 f0 = *reinterpret_cast<const f32x4*>(src);
  f32x4 f1 = *reinterpret_cast<const f32x4*>(src + 4);
  short8 v;
  __hip_bfloat16 h;
  h = __float2bfloat16(f0[0]); v[0] = *reinterpret_cast<short*>(&h);
  h = __float2bfloat16(f0[1]); v[1] = *reinterpret_cast<short*>(&h);
  h = __float2bfloat16(f0[2]); v[2] = *reinterpret_cast<short*>(&h);
  h = __float2bfloat16(f0[3]); v[3] = *reinterpret_cast<short*>(&h);
  h = __float2bfloat16(f1[0]); v[4] = *reinterpret_cast<short*>(&h);
  h = __float2bfloat16(f1[1]); v[5] = *reinterpret_cast<short*>(&h);
  h = __float2bfloat16(f1[2]); v[6] = *reinterpret_cast<short*>(&h);
  h = __float2bfloat16(f1[3]); v[7] = *reinterpret_cast<short*>(&h);
  return v;
}

// Hierarchical split-K: K splits 8x across blocks, 4x across a block's waves.
// Each wave: 64 out cols (4 B-frags) x 32 batch (2 A-frags) x 128 k, fragments
// loaded directly from global (16 rows x 128B per frag per k-step), fp32->bf16
// in-register. Wave partials combine in LDS; block partial atomicAdds into y.
__global__ __launch_bounds__(256, 4)
void bitnet_fused(const float* __restrict__ x,
                  const float* __restrict__ w,
                  const float* __restrict__ scale,
                  float* __restrict__ y)
{
  __shared__ float red[4][B_DIM][68];   // 34.8 KB, padded: lg-stride 272 -> 2-way

  const int tid   = threadIdx.x;
  const int lane  = tid & 63;
  const int wv    = tid >> 6;        // wave 0..3 -> k quarter within block
  const int l15   = lane & 15;
  const int lg    = lane >> 4;       // 0..3 -> k sub-group within MFMA
  const int obase = blockIdx.x * NT;
  const int k0    = blockIdx.y * KPB + wv * KPW;

  f32x4 acc[2][4];
#pragma unroll
  for (int m = 0; m < 2; ++m)
#pragma unroll
    for (int n = 0; n < 4; ++n)
      acc[m][n] = (f32x4){0.f, 0.f, 0.f, 0.f};

  const float* wbase = w + (size_t)(obase + l15) * IN_DIM + k0 + lg * 8;
  const float* xbase = x + (size_t)l15 * IN_DIM + k0 + lg * 8;

#pragma unroll 2
  for (int t = 0; t < KPW / 32; ++t) {   // 4 k-steps of 32
    const int kk = t * 32;
    short8 aa[2], bb[4];
#pragma unroll
    for (int m = 0; m < 2; ++m)
      aa[m] = cvt8(xbase + (size_t)m * 16 * IN_DIM + kk);
#pragma unroll
    for (int n = 0; n < 4; ++n)
      bb[n] = cvt8(wbase + (size_t)n * 16 * IN_DIM + kk);
#pragma unroll
    for (int m = 0; m < 2; ++m)
#pragma unroll
      for (int n = 0; n < 4; ++n)
        acc[m][n] = __builtin_amdgcn_mfma_f32_16x16x32_bf16(aa[m], bb[n], acc[m][n], 0, 0, 0);
  }

  // cross-wave K-combine in LDS
#pragma unroll
  for (int m = 0; m < 2; ++m)
#pragma unroll
    for (int n = 0; n < 4; ++n)
#pragma unroll
      for (int r = 0; r < 4; ++r)
        red[wv][m * 16 + lg * 4 + r][n * 16 + l15] = acc[m][n][r];
  __syncthreads();

  // block partial -> y via fp32 atomics (y zeroed by in-graph memset)
  const float sc = scale[0];
  const int c = tid & 63;            // local col, coalesced across lanes
  const int q = tid >> 6;            // batch quarter
#pragma unroll
  for (int i = 0; i < 8; ++i) {
    const int b = q * 8 + i;
    const float v = red[0][b][c] + red[1][b][c] + red[2][b][c] + red[3][b][c];
    atomicAdd(&y[(size_t)b * OUT_DIM + obase + c], v * sc);
  }
}

extern "C" void kernel_launch(void* const* d_in, const int* in_sizes, int n_in,
                              void* d_out, int out_size, void* d_ws, size_t ws_size,
                              hipStream_t stream) {
  const float* x = (const float*)d_in[0];
  const float* w = (const float*)d_in[1];
  const float* s = (const float*)d_in[2];
  float* y = (float*)d_out;
  hipMemsetAsync(y, 0, (size_t)out_size * sizeof(float), stream);
  bitnet_fused<<<dim3(OUT_DIM / NT, KSPL), 256, 0, stream>>>(x, w, s, y);
}